// Round 10
// baseline (681.166 us; speedup 1.0000x reference)
//
#include <hip/hip_runtime.h>
#include <math.h>
#include <stdint.h>

#define Nn 2048
#define Dd 128
#define Ee 8
#define NIT 8
#define KT (Nn*Ee)   // 16384
#define KSPLIT 32    // k-groups: 512 k each (64 s), 2 blocks/CU

typedef __bf16 bf16;
typedef __attribute__((ext_vector_type(8))) __bf16 bf16x8;
typedef __attribute__((ext_vector_type(4))) __bf16 bf16x4;
typedef __attribute__((ext_vector_type(4))) float f32x4;
typedef __attribute__((ext_vector_type(16))) float f32x16;

__device__ __forceinline__ f32x4 mfma16(bf16x8 a, bf16x8 b, f32x4 c){
    return __builtin_amdgcn_mfma_f32_16x16x32_bf16(a, b, c, 0, 0, 0);
}
__device__ __forceinline__ f32x16 mfma32(bf16x8 a, bf16x8 b, f32x16 c){
    return __builtin_amdgcn_mfma_f32_32x32x16_bf16(a, b, c, 0, 0, 0);
}
// async global->LDS, 16B per lane; LDS dest = wave-uniform base + lane*16
__device__ __forceinline__ void g2lds16(const void* g, void* l){
    __builtin_amdgcn_global_load_lds((const uint32_t*)g, (uint32_t*)l, 16, 0, 0);
}

// ---------------------------------------------------------------------------
// Prep (fp32 inputs): h fp32 master + bf16 copy; bf16-transposed weights.
// WmT[e][h][d], WiT[j][d], WhT[j][d], ArT[h][d]
// ---------------------------------------------------------------------------
__global__ __launch_bounds__(256) void k_prep(
    const float* __restrict__ node, const float* __restrict__ Wmsg,
    const float* __restrict__ Wi,   const float* __restrict__ Wh,
    const float* __restrict__ Ar,
    float* __restrict__ h32, bf16* __restrict__ hb,
    bf16* __restrict__ WmT, bf16* __restrict__ WiT, bf16* __restrict__ WhT,
    bf16* __restrict__ ArT)
{
    int tid = blockIdx.x*256 + threadIdx.x;
    int stride = gridDim.x*256;
    for (int i = tid; i < Nn*Dd; i += stride){
        float v = node[i]; h32[i] = v; hb[i] = (bf16)v;
    }
    for (int i = tid; i < Ee*Dd*Dd; i += stride){
        int e = i >> 14; int r = i & 16383; int h = r >> 7; int d = r & 127;
        WmT[i] = (bf16)Wmsg[e*Dd*Dd + d*Dd + h];
    }
    for (int i = tid; i < 384*Dd; i += stride){
        int j = i >> 7; int d = i & 127;
        WiT[i] = (bf16)Wi[d*384 + j];
        WhT[i] = (bf16)Wh[d*384 + j];
    }
    for (int i = tid; i < Dd*Dd; i += stride){
        int h = i >> 7; int d = i & 127;
        ArT[i] = (bf16)Ar[d*Dd + h];
    }
}

// ---------------------------------------------------------------------------
// Per-edge transform: Pt[s][h][e] = (hb @ W_e)[s][h]  (k-major layout)
// grid (32 s-tiles of 64, 8 h-tiles of 16), block 256 (4 waves x 16 s rows)
// ---------------------------------------------------------------------------
__global__ __launch_bounds__(256) void k_per_edge(
    const bf16* __restrict__ hb, const bf16* __restrict__ WmT,
    bf16* __restrict__ Pt)
{
    __shared__ bf16 Blds[Ee][16][Dd+8];             // 34,816 B
    const int s0 = blockIdx.x * 64;
    const int h0 = blockIdx.y * 16;
    const int tid = threadIdx.x;
    for (int i = 0; i < 8; i++){
        int idx = tid + i*256;                      // 2048 chunks of 8
        int e = idx >> 8, row = (idx >> 4) & 15, c = idx & 15;
        *(bf16x8*)&Blds[e][row][c*8] =
            *(const bf16x8*)&WmT[e*Dd*Dd + (h0+row)*Dd + c*8];
    }
    __syncthreads();
    const int lane = tid & 63, wave = tid >> 6;
    const int quad = lane >> 4, l16 = lane & 15;
    const int srow = s0 + wave*16 + l16;
    f32x4 acc[Ee];
    for (int e = 0; e < Ee; e++) acc[e] = (f32x4){0.f,0.f,0.f,0.f};
    for (int kk = 0; kk < 4; kk++){
        int k0 = kk*32 + quad*8;
        bf16x8 a = *(const bf16x8*)&hb[srow*Dd + k0];
        for (int e = 0; e < Ee; e++){
            bf16x8 b = *(const bf16x8*)&Blds[e][l16][k0];
            acc[e] = mfma16(a, b, acc[e]);
        }
    }
    const int h = h0 + l16;
    for (int r = 0; r < 4; r++){
        int s = s0 + wave*16 + quad*4 + r;
        bf16x8 po;
        for (int e = 0; e < Ee; e++) po[e] = (bf16)acc[e][r];
        *(bf16x8*)&Pt[((size_t)s*Dd + h)*Ee] = po;   // k-major [s][h][e]
    }
}

// ---------------------------------------------------------------------------
// msgP[kg][t][h] = sum_{k in group} edge[t][k] * Pt-as-B[h][k],  k = s*8+e
// R6 proven version: KSPLIT=32, 512 blocks (2/CU), 2-buffer 64KB pipeline,
// one-chunk lookahead. FIRST=1: fp32 edge read + in-register convert +
// persist bf16. XCD swizzle: kgroup = (flat&7)*4 + ((flat>>3)&3).
// PROBE ROUND 10: this kernel is launched TWICE per iteration (idempotent;
// second launch recomputes identical msgP). Delta vs R9 = 8 x its cost.
// ---------------------------------------------------------------------------
template<int FIRST>
__global__ __launch_bounds__(256) void k_msg_gemm(
    const float* __restrict__ edge_f, bf16* __restrict__ edge_bf,
    const bf16* __restrict__ Pt, bf16* __restrict__ msgP)
{
    __shared__ __align__(16) char ldsb[65536];      // 2 x 32KB Pt tiles
    const int flat = blockIdx.y*32 + blockIdx.x;    // grid (32,16) -> 512
    const int kgroup = (flat & 7)*4 + ((flat >> 3) & 3);
    const int tgroup = flat >> 5;
    const int t0 = tgroup * 128;
    const int sblk = kgroup * 64;                   // 64 s = 512 k per block
    const int tid = threadIdx.x;
    const int lane = tid & 63, wave = tid >> 6;
    const int half = lane >> 5, l31 = lane & 31;
    const int trow = t0 + wave*32 + l31;
    const char* Ptb = (const char*)Pt;

    f32x16 acc[4];
    #pragma unroll
    for (int nt = 0; nt < 4; nt++)
        for (int i = 0; i < 16; i++) acc[nt][i] = 0.f;

    bf16x8 A0[8], A1[8];

#define STAGE(ch_) do{                                                         \
    const char* _src = Ptb + (size_t)(sblk + (ch_)*16)*2048                    \
                           + wave*1024 + lane*16;                              \
    char* _dst = ldsb + ((ch_)&1)*32768 + wave*1024;                           \
    _Pragma("unroll")                                                          \
    for (int j = 0; j < 8; j++)                                                \
        g2lds16(_src + j*4096, _dst + j*4096);                                 \
}while(0)

#define PREF(AD_, ch_) do{                                                     \
    int _sc = sblk + (ch_)*16 + half;                                          \
    _Pragma("unroll")                                                          \
    for (int ks = 0; ks < 8; ks++){                                            \
        size_t _off = (size_t)(_sc + ks*2)*16384 + trow*8;                     \
        if (FIRST){                                                            \
            f32x4 _v0 = *(const f32x4*)&edge_f[_off];                          \
            f32x4 _v1 = *(const f32x4*)&edge_f[_off+4];                        \
            bf16x8 _o;                                                         \
            for (int _j = 0; _j < 4; _j++){                                    \
                _o[_j] = (bf16)_v0[_j]; _o[_j+4] = (bf16)_v1[_j];              \
            }                                                                  \
            AD_[ks] = _o;                                                      \
            *(bf16x8*)&edge_bf[_off] = _o;                                     \
        } else {                                                               \
            AD_[ks] = *(const bf16x8*)&edge_bf[_off];                          \
        }                                                                      \
    }                                                                          \
}while(0)

#define COMPUTE(AD_, ch_) do{                                                  \
    const bf16* _bt = (const bf16*)(ldsb + ((ch_)&1)*32768);                   \
    _Pragma("unroll")                                                          \
    for (int ks = 0; ks < 8; ks++){                                            \
        const bf16* _bp = _bt + (ks*2 + half)*1024 + l31*8;                    \
        acc[0] = mfma32(AD_[ks], *(const bf16x8*)(_bp      ), acc[0]);         \
        acc[1] = mfma32(AD_[ks], *(const bf16x8*)(_bp + 256), acc[1]);         \
        acc[2] = mfma32(AD_[ks], *(const bf16x8*)(_bp + 512), acc[2]);         \
        acc[3] = mfma32(AD_[ks], *(const bf16x8*)(_bp + 768), acc[3]);         \
    }                                                                          \
}while(0)

    STAGE(0); PREF(A0, 0);
    asm volatile("s_waitcnt vmcnt(0)" ::: "memory");
    __syncthreads();
    #pragma unroll
    for (int cc = 0; cc < 2; cc++){
        const int ch = cc*2;
        STAGE(ch+1); PREF(A1, ch+1);
        COMPUTE(A0, ch);
        asm volatile("s_waitcnt vmcnt(0)" ::: "memory");
        __syncthreads();
        if (ch+2 < 4){ STAGE(ch+2); PREF(A0, ch+2); }
        COMPUTE(A1, ch+1);
        if (ch+2 < 4){
            asm volatile("s_waitcnt vmcnt(0)" ::: "memory");
            __syncthreads();
        }
    }
#undef STAGE
#undef PREF
#undef COMPUTE

    // C/D layout 32x32: col = lane&31, row = (r&3) + 8*(r>>2) + 4*(lane>>5)
    bf16* dst = msgP + (size_t)kgroup*(Nn*Dd);
    #pragma unroll
    for (int nt = 0; nt < 4; nt++){
        int h = nt*32 + l31;
        #pragma unroll
        for (int r = 0; r < 16; r++){
            int row = (r&3) + 8*(r>>2) + 4*half;
            dst[(size_t)(t0 + wave*32 + row)*Dd + h] = (bf16)acc[nt][r];
        }
    }
}

// ---------------------------------------------------------------------------
// GRU with pre-GEMM phase-A reduce (R9 proven): 256 threads cover the
// 16x128 msg tile exactly once; 32 bf16 partials + b_msg summed in fp32
// p-order, single bf16 round; staged to msg_b LDS; Gi A-operand from LDS.
// ---------------------------------------------------------------------------
__global__ __launch_bounds__(256) void k_gru2(
    const bf16* __restrict__ msgP, const float* __restrict__ bmsg,
    const bf16* __restrict__ WiT, const bf16* __restrict__ WhT,
    const float* __restrict__ bgru,
    float* __restrict__ h32, bf16* __restrict__ hb)
{
    __shared__ __align__(16) bf16 stage[384][40];   // 30,720 B
    __shared__ float Gs[16][384];                    // 24,576 B
    __shared__ float Ghn[16][128];                   //  8,192 B
    __shared__ __align__(16) bf16 msg_b[16][136];    //  4,352 B (67,840 total)

    const int t0 = blockIdx.x * 16;
    const int tid = threadIdx.x;
    const int lane = tid & 63, wave = tid >> 6;
    const int quad = lane >> 4, l16 = lane & 15;

    // ---- Phase A: reduce KSPLIT partials + b_msg -> msg_b (once) ----
    {
        int m = tid >> 4;                 // 0..15
        int d0 = (tid & 15) * 8;          // 0..120
        f32x4 s0 = *(const f32x4*)&bmsg[d0];
        f32x4 s1 = *(const f32x4*)&bmsg[d0+4];
        #pragma unroll
        for (int p = 0; p < KSPLIT; p++){
            bf16x8 v = *(const bf16x8*)&msgP[(size_t)p*Nn*Dd + (t0+m)*Dd + d0];
            #pragma unroll
            for (int j = 0; j < 4; j++){
                s0[j] += (float)v[j];
                s1[j] += (float)v[j+4];
            }
        }
        bf16x8 o;
        #pragma unroll
        for (int j = 0; j < 4; j++){ o[j] = (bf16)s0[j]; o[j+4] = (bf16)s1[j]; }
        *(bf16x8*)&msg_b[m][d0] = o;
    }
    __syncthreads();

    // ---- Phase B: Gi/Gh GEMMs (Gi A-operand from LDS) ----
    f32x4 accA[6], accB[6];
    for (int i = 0; i < 6; i++){ accA[i] = (f32x4){0.f,0.f,0.f,0.f}; accB[i] = (f32x4){0.f,0.f,0.f,0.f}; }

    for (int mat = 0; mat < 2; mat++){
        const bf16* WT = mat == 0 ? WiT : WhT;
        for (int kc = 0; kc < 4; kc++){
            for (int i = 0; i < 6; i++){
                int idx = tid + i*256; int row = idx >> 2, c = idx & 3;
                *(bf16x8*)&stage[row][c*8] = *(const bf16x8*)&WT[row*Dd + kc*32 + c*8];
            }
            __syncthreads();
            int k0 = kc*32 + quad*8;
            bf16x8 a;
            if (mat == 0) a = *(const bf16x8*)&msg_b[l16][k0];
            else          a = *(const bf16x8*)&hb[(t0 + l16)*Dd + k0];
            for (int tt = 0; tt < 6; tt++){
                int T = wave*6 + tt;
                bf16x8 b = *(const bf16x8*)&stage[T*16 + l16][quad*8];
                if (mat == 0 || T < 16) accA[tt] = mfma16(a, b, accA[tt]);
                else                    accB[tt] = mfma16(a, b, accB[tt]);
            }
            __syncthreads();
        }
    }
    for (int tt = 0; tt < 6; tt++){
        int T = wave*6 + tt;
        int j = T*16 + l16;
        for (int r = 0; r < 4; r++){
            int m = quad*4 + r;
            Gs[m][j] = accA[tt][r];
            if (T >= 16) Ghn[m][j - 256] = accB[tt][r];
        }
    }
    __syncthreads();

    // ---- Phase C: gates + h update ----
    for (int i = 0; i < 8; i++){
        int cell = tid + i*256;
        int m = cell >> 7, jd = cell & 127;
        int t = t0 + m;
        float xr = Gs[m][jd]       + bgru[jd];
        float xz = Gs[m][jd + 128] + bgru[jd + 128];
        float xn = Gs[m][jd + 256] + bgru[jd + 256];
        float r = 1.f / (1.f + expf(-xr));
        float z = 1.f / (1.f + expf(-xz));
        float n = tanhf(xn + r * Ghn[m][jd]);
        float ho = h32[t*Dd + jd];
        float hnew = (1.f - z) * n + z * ho;
        h32[t*Dd + jd] = hnew;
        hb [t*Dd + jd] = (bf16)hnew;
    }
}

// ---------------------------------------------------------------------------
// Readout 1: t1 = hb @ A_readout  (via ArT[h][d]), bf16 out (internal)
// ---------------------------------------------------------------------------
__global__ __launch_bounds__(256) void k_read1(
    const bf16* __restrict__ hb, const bf16* __restrict__ ArT, bf16* __restrict__ t1)
{
    __shared__ bf16 Blds[Dd][Dd+8];
    const int s0 = blockIdx.x * 64;
    const int tid = threadIdx.x;
    for (int i = 0; i < 8; i++){
        int idx = tid + i*256; int row = idx >> 4, c = idx & 15;
        *(bf16x8*)&Blds[row][c*8] = *(const bf16x8*)&ArT[row*Dd + c*8];
    }
    __syncthreads();
    const int lane = tid & 63, wave = tid >> 6;
    const int quad = lane >> 4, l16 = lane & 15;
    const int srow = s0 + wave*16 + l16;
    f32x4 acc[8];
    for (int nt = 0; nt < 8; nt++) acc[nt] = (f32x4){0.f,0.f,0.f,0.f};
    for (int kk = 0; kk < 4; kk++){
        int k0 = kk*32 + quad*8;
        bf16x8 a = *(const bf16x8*)&hb[srow*Dd + k0];
        for (int nt = 0; nt < 8; nt++){
            bf16x8 b = *(const bf16x8*)&Blds[nt*16 + l16][k0];
            acc[nt] = mfma16(a, b, acc[nt]);
        }
    }
    for (int nt = 0; nt < 8; nt++){
        int h = nt*16 + l16;
        for (int r = 0; r < 4; r++){
            int s = s0 + wave*16 + quad*4 + r;
            t1[s*Dd + h] = (bf16)acc[nt][r];
        }
    }
}

// ---------------------------------------------------------------------------
// Readout 2: logits[i][j] = sum_d t1[i][d]*hb[j][d], fp32 out
// ---------------------------------------------------------------------------
__global__ __launch_bounds__(256) void k_read2(
    const bf16* __restrict__ t1, const bf16* __restrict__ hb, float* __restrict__ out)
{
    const int i0 = blockIdx.x * 64, j0 = blockIdx.y * 128;
    const int tid = threadIdx.x;
    const int lane = tid & 63, wave = tid >> 6;
    const int quad = lane >> 4, l16 = lane & 15;
    const int irow = i0 + wave*16 + l16;
    f32x4 acc[8];
    for (int nt = 0; nt < 8; nt++) acc[nt] = (f32x4){0.f,0.f,0.f,0.f};
    for (int kk = 0; kk < 4; kk++){
        int k0 = kk*32 + quad*8;
        bf16x8 a = *(const bf16x8*)&t1[irow*Dd + k0];
        for (int nt = 0; nt < 8; nt++){
            int j = j0 + nt*16 + l16;
            bf16x8 b = *(const bf16x8*)&hb[j*Dd + k0];
            acc[nt] = mfma16(a, b, acc[nt]);
        }
    }
    for (int nt = 0; nt < 8; nt++){
        int j = j0 + nt*16 + l16;
        for (int r = 0; r < 4; r++){
            int irw = i0 + wave*16 + quad*4 + r;
            out[(size_t)irw*Nn + j] = acc[nt][r];
        }
    }
}

// ---------------------------------------------------------------------------
extern "C" void kernel_launch(void* const* d_in, const int* in_sizes, int n_in,
                              void* d_out, int out_size, void* d_ws, size_t ws_size,
                              hipStream_t stream)
{
    const float* node = (const float*)d_in[0];
    const float* edge = (const float*)d_in[1];
    const float* Wmsg = (const float*)d_in[2];
    const float* bmsg = (const float*)d_in[3];
    const float* Wi   = (const float*)d_in[4];
    const float* Wh   = (const float*)d_in[5];
    const float* bgru = (const float*)d_in[6];
    const float* Ar   = (const float*)d_in[7];
    float* out = (float*)d_out;

    char* ws = (char*)d_ws;
    bf16*  edge_bf = (bf16*)ws;          ws += (size_t)Nn*Nn*Ee*2;      // 64 MiB
    bf16*  msgP = (bf16*)ws;             ws += (size_t)KSPLIT*Nn*Dd*2;  // 16 MiB
    bf16*  Pt  = (bf16*)ws;              ws += (size_t)Dd*KT*2;         //  4 MiB
    float* h32 = (float*)ws;             ws += (size_t)Nn*Dd*4;
    bf16*  hb  = (bf16*)ws;              ws += (size_t)Nn*Dd*2;
    bf16*  WmT = (bf16*)ws;              ws += (size_t)Ee*Dd*Dd*2;
    bf16*  WiT = (bf16*)ws;              ws += (size_t)384*Dd*2;
    bf16*  WhT = (bf16*)ws;              ws += (size_t)384*Dd*2;
    bf16*  ArT = (bf16*)ws;              ws += (size_t)Dd*Dd*2;
    bf16*  t1  = (bf16*)ws;              ws += (size_t)Nn*Dd*2;

    k_prep<<<dim3(256), 256, 0, stream>>>(node, Wmsg, Wi, Wh, Ar,
                                          h32, hb, WmT, WiT, WhT, ArT);
    for (int it = 0; it < NIT; it++){
        k_per_edge<<<dim3(32, 8), 256, 0, stream>>>(hb, WmT, Pt);
        // PROBE: msg_gemm launched twice (idempotent). Delta = 8 x T_mg.
        if (it == 0){
            k_msg_gemm<1><<<dim3(32,16), 256, 0, stream>>>(edge, edge_bf, Pt, msgP);
            k_msg_gemm<0><<<dim3(32,16), 256, 0, stream>>>(edge, edge_bf, Pt, msgP);
        } else {
            k_msg_gemm<0><<<dim3(32,16), 256, 0, stream>>>(edge, edge_bf, Pt, msgP);
            k_msg_gemm<0><<<dim3(32,16), 256, 0, stream>>>(edge, edge_bf, Pt, msgP);
        }
        k_gru2<<<dim3(128), 256, 0, stream>>>(msgP, bmsg, WiT, WhT, bgru, h32, hb);
    }
    k_read1<<<dim3(32),     256, 0, stream>>>(hb, ArT, t1);
    k_read2<<<dim3(32, 16), 256, 0, stream>>>(t1, hb, out);
}

// Round 11
// 577.343 us; speedup vs baseline: 1.1798x; 1.1798x over previous
//
#include <hip/hip_runtime.h>
#include <math.h>
#include <stdint.h>

#define Nn 2048
#define Dd 128
#define Ee 8
#define NIT 8
#define KT (Nn*Ee)   // 16384
#define KSPLIT 32    // k-groups: 512 k each (64 s), 2 blocks/CU

typedef __bf16 bf16;
typedef __attribute__((ext_vector_type(8))) __bf16 bf16x8;
typedef __attribute__((ext_vector_type(4))) __bf16 bf16x4;
typedef __attribute__((ext_vector_type(4))) float f32x4;
typedef __attribute__((ext_vector_type(16))) float f32x16;

__device__ __forceinline__ f32x4 mfma16(bf16x8 a, bf16x8 b, f32x4 c){
    return __builtin_amdgcn_mfma_f32_16x16x32_bf16(a, b, c, 0, 0, 0);
}
__device__ __forceinline__ f32x16 mfma32(bf16x8 a, bf16x8 b, f32x16 c){
    return __builtin_amdgcn_mfma_f32_32x32x16_bf16(a, b, c, 0, 0, 0);
}
// async global->LDS, 16B per lane; LDS dest = wave-uniform base + lane*16
__device__ __forceinline__ void g2lds16(const void* g, void* l){
    __builtin_amdgcn_global_load_lds((const uint32_t*)g, (uint32_t*)l, 16, 0, 0);
}

// ---------------------------------------------------------------------------
// Prep (fp32 inputs): h fp32 master + bf16 copy; bf16-transposed weights.
// WmT[e][h][d], WiT[j][d], WhT[j][d], ArT[h][d]
// ---------------------------------------------------------------------------
__global__ __launch_bounds__(256) void k_prep(
    const float* __restrict__ node, const float* __restrict__ Wmsg,
    const float* __restrict__ Wi,   const float* __restrict__ Wh,
    const float* __restrict__ Ar,
    float* __restrict__ h32, bf16* __restrict__ hb,
    bf16* __restrict__ WmT, bf16* __restrict__ WiT, bf16* __restrict__ WhT,
    bf16* __restrict__ ArT)
{
    int tid = blockIdx.x*256 + threadIdx.x;
    int stride = gridDim.x*256;
    for (int i = tid; i < Nn*Dd; i += stride){
        float v = node[i]; h32[i] = v; hb[i] = (bf16)v;
    }
    for (int i = tid; i < Ee*Dd*Dd; i += stride){
        int e = i >> 14; int r = i & 16383; int h = r >> 7; int d = r & 127;
        WmT[i] = (bf16)Wmsg[e*Dd*Dd + d*Dd + h];
    }
    for (int i = tid; i < 384*Dd; i += stride){
        int j = i >> 7; int d = i & 127;
        WiT[i] = (bf16)Wi[d*384 + j];
        WhT[i] = (bf16)Wh[d*384 + j];
    }
    for (int i = tid; i < Dd*Dd; i += stride){
        int h = i >> 7; int d = i & 127;
        ArT[i] = (bf16)Ar[d*Dd + h];
    }
}

// ---------------------------------------------------------------------------
// Per-edge transform: Pt[s][h][e] = (hb @ W_e)[s][h]  (k-major layout)
// grid (32 s-tiles of 64, 8 h-tiles of 16), block 256 (4 waves x 16 s rows)
// PROBE ROUND 11: launched TWICE per iteration (pure function of hb/WmT;
// second launch writes identical Pt). Delta vs R9 = 8 x its cost.
// ---------------------------------------------------------------------------
__global__ __launch_bounds__(256) void k_per_edge(
    const bf16* __restrict__ hb, const bf16* __restrict__ WmT,
    bf16* __restrict__ Pt)
{
    __shared__ bf16 Blds[Ee][16][Dd+8];             // 34,816 B
    const int s0 = blockIdx.x * 64;
    const int h0 = blockIdx.y * 16;
    const int tid = threadIdx.x;
    for (int i = 0; i < 8; i++){
        int idx = tid + i*256;                      // 2048 chunks of 8
        int e = idx >> 8, row = (idx >> 4) & 15, c = idx & 15;
        *(bf16x8*)&Blds[e][row][c*8] =
            *(const bf16x8*)&WmT[e*Dd*Dd + (h0+row)*Dd + c*8];
    }
    __syncthreads();
    const int lane = tid & 63, wave = tid >> 6;
    const int quad = lane >> 4, l16 = lane & 15;
    const int srow = s0 + wave*16 + l16;
    f32x4 acc[Ee];
    for (int e = 0; e < Ee; e++) acc[e] = (f32x4){0.f,0.f,0.f,0.f};
    for (int kk = 0; kk < 4; kk++){
        int k0 = kk*32 + quad*8;
        bf16x8 a = *(const bf16x8*)&hb[srow*Dd + k0];
        for (int e = 0; e < Ee; e++){
            bf16x8 b = *(const bf16x8*)&Blds[e][l16][k0];
            acc[e] = mfma16(a, b, acc[e]);
        }
    }
    const int h = h0 + l16;
    for (int r = 0; r < 4; r++){
        int s = s0 + wave*16 + quad*4 + r;
        bf16x8 po;
        for (int e = 0; e < Ee; e++) po[e] = (bf16)acc[e][r];
        *(bf16x8*)&Pt[((size_t)s*Dd + h)*Ee] = po;   // k-major [s][h][e]
    }
}

// ---------------------------------------------------------------------------
// msgP[kg][t][h] = sum_{k in group} edge[t][k] * Pt-as-B[h][k],  k = s*8+e
// R6 proven version: KSPLIT=32, 512 blocks (2/CU), 2-buffer 64KB pipeline,
// one-chunk lookahead. FIRST=1: fp32 edge read + in-register convert +
// persist bf16. XCD swizzle: kgroup = (flat&7)*4 + ((flat>>3)&3).
// ---------------------------------------------------------------------------
template<int FIRST>
__global__ __launch_bounds__(256) void k_msg_gemm(
    const float* __restrict__ edge_f, bf16* __restrict__ edge_bf,
    const bf16* __restrict__ Pt, bf16* __restrict__ msgP)
{
    __shared__ __align__(16) char ldsb[65536];      // 2 x 32KB Pt tiles
    const int flat = blockIdx.y*32 + blockIdx.x;    // grid (32,16) -> 512
    const int kgroup = (flat & 7)*4 + ((flat >> 3) & 3);
    const int tgroup = flat >> 5;
    const int t0 = tgroup * 128;
    const int sblk = kgroup * 64;                   // 64 s = 512 k per block
    const int tid = threadIdx.x;
    const int lane = tid & 63, wave = tid >> 6;
    const int half = lane >> 5, l31 = lane & 31;
    const int trow = t0 + wave*32 + l31;
    const char* Ptb = (const char*)Pt;

    f32x16 acc[4];
    #pragma unroll
    for (int nt = 0; nt < 4; nt++)
        for (int i = 0; i < 16; i++) acc[nt][i] = 0.f;

    bf16x8 A0[8], A1[8];

#define STAGE(ch_) do{                                                         \
    const char* _src = Ptb + (size_t)(sblk + (ch_)*16)*2048                    \
                           + wave*1024 + lane*16;                              \
    char* _dst = ldsb + ((ch_)&1)*32768 + wave*1024;                           \
    _Pragma("unroll")                                                          \
    for (int j = 0; j < 8; j++)                                                \
        g2lds16(_src + j*4096, _dst + j*4096);                                 \
}while(0)

#define PREF(AD_, ch_) do{                                                     \
    int _sc = sblk + (ch_)*16 + half;                                          \
    _Pragma("unroll")                                                          \
    for (int ks = 0; ks < 8; ks++){                                            \
        size_t _off = (size_t)(_sc + ks*2)*16384 + trow*8;                     \
        if (FIRST){                                                            \
            f32x4 _v0 = *(const f32x4*)&edge_f[_off];                          \
            f32x4 _v1 = *(const f32x4*)&edge_f[_off+4];                        \
            bf16x8 _o;                                                         \
            for (int _j = 0; _j < 4; _j++){                                    \
                _o[_j] = (bf16)_v0[_j]; _o[_j+4] = (bf16)_v1[_j];              \
            }                                                                  \
            AD_[ks] = _o;                                                      \
            *(bf16x8*)&edge_bf[_off] = _o;                                     \
        } else {                                                               \
            AD_[ks] = *(const bf16x8*)&edge_bf[_off];                          \
        }                                                                      \
    }                                                                          \
}while(0)

#define COMPUTE(AD_, ch_) do{                                                  \
    const bf16* _bt = (const bf16*)(ldsb + ((ch_)&1)*32768);                   \
    _Pragma("unroll")                                                          \
    for (int ks = 0; ks < 8; ks++){                                            \
        const bf16* _bp = _bt + (ks*2 + half)*1024 + l31*8;                    \
        acc[0] = mfma32(AD_[ks], *(const bf16x8*)(_bp      ), acc[0]);         \
        acc[1] = mfma32(AD_[ks], *(const bf16x8*)(_bp + 256), acc[1]);         \
        acc[2] = mfma32(AD_[ks], *(const bf16x8*)(_bp + 512), acc[2]);         \
        acc[3] = mfma32(AD_[ks], *(const bf16x8*)(_bp + 768), acc[3]);         \
    }                                                                          \
}while(0)

    STAGE(0); PREF(A0, 0);
    asm volatile("s_waitcnt vmcnt(0)" ::: "memory");
    __syncthreads();
    #pragma unroll
    for (int cc = 0; cc < 2; cc++){
        const int ch = cc*2;
        STAGE(ch+1); PREF(A1, ch+1);
        COMPUTE(A0, ch);
        asm volatile("s_waitcnt vmcnt(0)" ::: "memory");
        __syncthreads();
        if (ch+2 < 4){ STAGE(ch+2); PREF(A0, ch+2); }
        COMPUTE(A1, ch+1);
        if (ch+2 < 4){
            asm volatile("s_waitcnt vmcnt(0)" ::: "memory");
            __syncthreads();
        }
    }
#undef STAGE
#undef PREF
#undef COMPUTE

    // C/D layout 32x32: col = lane&31, row = (r&3) + 8*(r>>2) + 4*(lane>>5)
    bf16* dst = msgP + (size_t)kgroup*(Nn*Dd);
    #pragma unroll
    for (int nt = 0; nt < 4; nt++){
        int h = nt*32 + l31;
        #pragma unroll
        for (int r = 0; r < 16; r++){
            int row = (r&3) + 8*(r>>2) + 4*half;
            dst[(size_t)(t0 + wave*32 + row)*Dd + h] = (bf16)acc[nt][r];
        }
    }
}

// ---------------------------------------------------------------------------
// GRU with pre-GEMM phase-A reduce (R9 proven): 256 threads cover the
// 16x128 msg tile exactly once; 32 bf16 partials + b_msg summed in fp32
// p-order, single bf16 round; staged to msg_b LDS; Gi A-operand from LDS.
// ---------------------------------------------------------------------------
__global__ __launch_bounds__(256) void k_gru2(
    const bf16* __restrict__ msgP, const float* __restrict__ bmsg,
    const bf16* __restrict__ WiT, const bf16* __restrict__ WhT,
    const float* __restrict__ bgru,
    float* __restrict__ h32, bf16* __restrict__ hb)
{
    __shared__ __align__(16) bf16 stage[384][40];   // 30,720 B
    __shared__ float Gs[16][384];                    // 24,576 B
    __shared__ float Ghn[16][128];                   //  8,192 B
    __shared__ __align__(16) bf16 msg_b[16][136];    //  4,352 B (67,840 total)

    const int t0 = blockIdx.x * 16;
    const int tid = threadIdx.x;
    const int lane = tid & 63, wave = tid >> 6;
    const int quad = lane >> 4, l16 = lane & 15;

    // ---- Phase A: reduce KSPLIT partials + b_msg -> msg_b (once) ----
    {
        int m = tid >> 4;                 // 0..15
        int d0 = (tid & 15) * 8;          // 0..120
        f32x4 s0 = *(const f32x4*)&bmsg[d0];
        f32x4 s1 = *(const f32x4*)&bmsg[d0+4];
        #pragma unroll
        for (int p = 0; p < KSPLIT; p++){
            bf16x8 v = *(const bf16x8*)&msgP[(size_t)p*Nn*Dd + (t0+m)*Dd + d0];
            #pragma unroll
            for (int j = 0; j < 4; j++){
                s0[j] += (float)v[j];
                s1[j] += (float)v[j+4];
            }
        }
        bf16x8 o;
        #pragma unroll
        for (int j = 0; j < 4; j++){ o[j] = (bf16)s0[j]; o[j+4] = (bf16)s1[j]; }
        *(bf16x8*)&msg_b[m][d0] = o;
    }
    __syncthreads();

    // ---- Phase B: Gi/Gh GEMMs (Gi A-operand from LDS) ----
    f32x4 accA[6], accB[6];
    for (int i = 0; i < 6; i++){ accA[i] = (f32x4){0.f,0.f,0.f,0.f}; accB[i] = (f32x4){0.f,0.f,0.f,0.f}; }

    for (int mat = 0; mat < 2; mat++){
        const bf16* WT = mat == 0 ? WiT : WhT;
        for (int kc = 0; kc < 4; kc++){
            for (int i = 0; i < 6; i++){
                int idx = tid + i*256; int row = idx >> 2, c = idx & 3;
                *(bf16x8*)&stage[row][c*8] = *(const bf16x8*)&WT[row*Dd + kc*32 + c*8];
            }
            __syncthreads();
            int k0 = kc*32 + quad*8;
            bf16x8 a;
            if (mat == 0) a = *(const bf16x8*)&msg_b[l16][k0];
            else          a = *(const bf16x8*)&hb[(t0 + l16)*Dd + k0];
            for (int tt = 0; tt < 6; tt++){
                int T = wave*6 + tt;
                bf16x8 b = *(const bf16x8*)&stage[T*16 + l16][quad*8];
                if (mat == 0 || T < 16) accA[tt] = mfma16(a, b, accA[tt]);
                else                    accB[tt] = mfma16(a, b, accB[tt]);
            }
            __syncthreads();
        }
    }
    for (int tt = 0; tt < 6; tt++){
        int T = wave*6 + tt;
        int j = T*16 + l16;
        for (int r = 0; r < 4; r++){
            int m = quad*4 + r;
            Gs[m][j] = accA[tt][r];
            if (T >= 16) Ghn[m][j - 256] = accB[tt][r];
        }
    }
    __syncthreads();

    // ---- Phase C: gates + h update ----
    for (int i = 0; i < 8; i++){
        int cell = tid + i*256;
        int m = cell >> 7, jd = cell & 127;
        int t = t0 + m;
        float xr = Gs[m][jd]       + bgru[jd];
        float xz = Gs[m][jd + 128] + bgru[jd + 128];
        float xn = Gs[m][jd + 256] + bgru[jd + 256];
        float r = 1.f / (1.f + expf(-xr));
        float z = 1.f / (1.f + expf(-xz));
        float n = tanhf(xn + r * Ghn[m][jd]);
        float ho = h32[t*Dd + jd];
        float hnew = (1.f - z) * n + z * ho;
        h32[t*Dd + jd] = hnew;
        hb [t*Dd + jd] = (bf16)hnew;
    }
}

// ---------------------------------------------------------------------------
// Readout 1: t1 = hb @ A_readout  (via ArT[h][d]), bf16 out (internal)
// ---------------------------------------------------------------------------
__global__ __launch_bounds__(256) void k_read1(
    const bf16* __restrict__ hb, const bf16* __restrict__ ArT, bf16* __restrict__ t1)
{
    __shared__ bf16 Blds[Dd][Dd+8];
    const int s0 = blockIdx.x * 64;
    const int tid = threadIdx.x;
    for (int i = 0; i < 8; i++){
        int idx = tid + i*256; int row = idx >> 4, c = idx & 15;
        *(bf16x8*)&Blds[row][c*8] = *(const bf16x8*)&ArT[row*Dd + c*8];
    }
    __syncthreads();
    const int lane = tid & 63, wave = tid >> 6;
    const int quad = lane >> 4, l16 = lane & 15;
    const int srow = s0 + wave*16 + l16;
    f32x4 acc[8];
    for (int nt = 0; nt < 8; nt++) acc[nt] = (f32x4){0.f,0.f,0.f,0.f};
    for (int kk = 0; kk < 4; kk++){
        int k0 = kk*32 + quad*8;
        bf16x8 a = *(const bf16x8*)&hb[srow*Dd + k0];
        for (int nt = 0; nt < 8; nt++){
            bf16x8 b = *(const bf16x8*)&Blds[nt*16 + l16][k0];
            acc[nt] = mfma16(a, b, acc[nt]);
        }
    }
    for (int nt = 0; nt < 8; nt++){
        int h = nt*16 + l16;
        for (int r = 0; r < 4; r++){
            int s = s0 + wave*16 + quad*4 + r;
            t1[s*Dd + h] = (bf16)acc[nt][r];
        }
    }
}

// ---------------------------------------------------------------------------
// Readout 2: logits[i][j] = sum_d t1[i][d]*hb[j][d], fp32 out
// ---------------------------------------------------------------------------
__global__ __launch_bounds__(256) void k_read2(
    const bf16* __restrict__ t1, const bf16* __restrict__ hb, float* __restrict__ out)
{
    const int i0 = blockIdx.x * 64, j0 = blockIdx.y * 128;
    const int tid = threadIdx.x;
    const int lane = tid & 63, wave = tid >> 6;
    const int quad = lane >> 4, l16 = lane & 15;
    const int irow = i0 + wave*16 + l16;
    f32x4 acc[8];
    for (int nt = 0; nt < 8; nt++) acc[nt] = (f32x4){0.f,0.f,0.f,0.f};
    for (int kk = 0; kk < 4; kk++){
        int k0 = kk*32 + quad*8;
        bf16x8 a = *(const bf16x8*)&t1[irow*Dd + k0];
        for (int nt = 0; nt < 8; nt++){
            int j = j0 + nt*16 + l16;
            bf16x8 b = *(const bf16x8*)&hb[j*Dd + k0];
            acc[nt] = mfma16(a, b, acc[nt]);
        }
    }
    for (int nt = 0; nt < 8; nt++){
        int j = j0 + nt*16 + l16;
        for (int r = 0; r < 4; r++){
            int irw = i0 + wave*16 + quad*4 + r;
            out[(size_t)irw*Nn + j] = acc[nt][r];
        }
    }
}

// ---------------------------------------------------------------------------
extern "C" void kernel_launch(void* const* d_in, const int* in_sizes, int n_in,
                              void* d_out, int out_size, void* d_ws, size_t ws_size,
                              hipStream_t stream)
{
    const float* node = (const float*)d_in[0];
    const float* edge = (const float*)d_in[1];
    const float* Wmsg = (const float*)d_in[2];
    const float* bmsg = (const float*)d_in[3];
    const float* Wi   = (const float*)d_in[4];
    const float* Wh   = (const float*)d_in[5];
    const float* bgru = (const float*)d_in[6];
    const float* Ar   = (const float*)d_in[7];
    float* out = (float*)d_out;

    char* ws = (char*)d_ws;
    bf16*  edge_bf = (bf16*)ws;          ws += (size_t)Nn*Nn*Ee*2;      // 64 MiB
    bf16*  msgP = (bf16*)ws;             ws += (size_t)KSPLIT*Nn*Dd*2;  // 16 MiB
    bf16*  Pt  = (bf16*)ws;              ws += (size_t)Dd*KT*2;         //  4 MiB
    float* h32 = (float*)ws;             ws += (size_t)Nn*Dd*4;
    bf16*  hb  = (bf16*)ws;              ws += (size_t)Nn*Dd*2;
    bf16*  WmT = (bf16*)ws;              ws += (size_t)Ee*Dd*Dd*2;
    bf16*  WiT = (bf16*)ws;              ws += (size_t)384*Dd*2;
    bf16*  WhT = (bf16*)ws;              ws += (size_t)384*Dd*2;
    bf16*  ArT = (bf16*)ws;              ws += (size_t)Dd*Dd*2;
    bf16*  t1  = (bf16*)ws;              ws += (size_t)Nn*Dd*2;

    k_prep<<<dim3(256), 256, 0, stream>>>(node, Wmsg, Wi, Wh, Ar,
                                          h32, hb, WmT, WiT, WhT, ArT);
    for (int it = 0; it < NIT; it++){
        // PROBE: per_edge launched twice (idempotent). Delta = 8 x T_pe.
        k_per_edge<<<dim3(32, 8), 256, 0, stream>>>(hb, WmT, Pt);
        k_per_edge<<<dim3(32, 8), 256, 0, stream>>>(hb, WmT, Pt);
        if (it == 0)
            k_msg_gemm<1><<<dim3(32,16), 256, 0, stream>>>(edge, edge_bf, Pt, msgP);
        else
            k_msg_gemm<0><<<dim3(32,16), 256, 0, stream>>>(edge, edge_bf, Pt, msgP);
        k_gru2<<<dim3(128), 256, 0, stream>>>(msgP, bmsg, WiT, WhT, bgru, h32, hb);
    }
    k_read1<<<dim3(32),     256, 0, stream>>>(hb, ArT, t1);
    k_read2<<<dim3(32, 16), 256, 0, stream>>>(t1, hb, out);
}

// Round 12
// 525.627 us; speedup vs baseline: 1.2959x; 1.0984x over previous
//
#include <hip/hip_runtime.h>
#include <math.h>
#include <stdint.h>

#define Nn 2048
#define Dd 128
#define Ee 8
#define NIT 8
#define KT (Nn*Ee)   // 16384
#define KSPLIT 32    // k-groups: 512 k each (64 s), 2 blocks/CU

typedef __bf16 bf16;
typedef __attribute__((ext_vector_type(8))) __bf16 bf16x8;
typedef __attribute__((ext_vector_type(4))) __bf16 bf16x4;
typedef __attribute__((ext_vector_type(4))) float f32x4;
typedef __attribute__((ext_vector_type(16))) float f32x16;

__device__ __forceinline__ f32x4 mfma16(bf16x8 a, bf16x8 b, f32x4 c){
    return __builtin_amdgcn_mfma_f32_16x16x32_bf16(a, b, c, 0, 0, 0);
}
__device__ __forceinline__ f32x16 mfma32(bf16x8 a, bf16x8 b, f32x16 c){
    return __builtin_amdgcn_mfma_f32_32x32x16_bf16(a, b, c, 0, 0, 0);
}
// async global->LDS, 16B per lane; LDS dest = wave-uniform base + lane*16
__device__ __forceinline__ void g2lds16(const void* g, void* l){
    __builtin_amdgcn_global_load_lds((const uint32_t*)g, (uint32_t*)l, 16, 0, 0);
}

// ---------------------------------------------------------------------------
// Prep (fp32 inputs): h fp32 master + bf16 copy; bf16-transposed weights.
// WmT[e][h][d], WiT[j][d], WhT[j][d], ArT[h][d]
// ---------------------------------------------------------------------------
__global__ __launch_bounds__(256) void k_prep(
    const float* __restrict__ node, const float* __restrict__ Wmsg,
    const float* __restrict__ Wi,   const float* __restrict__ Wh,
    const float* __restrict__ Ar,
    float* __restrict__ h32, bf16* __restrict__ hb,
    bf16* __restrict__ WmT, bf16* __restrict__ WiT, bf16* __restrict__ WhT,
    bf16* __restrict__ ArT)
{
    int tid = blockIdx.x*256 + threadIdx.x;
    int stride = gridDim.x*256;
    for (int i = tid; i < Nn*Dd; i += stride){
        float v = node[i]; h32[i] = v; hb[i] = (bf16)v;
    }
    for (int i = tid; i < Ee*Dd*Dd; i += stride){
        int e = i >> 14; int r = i & 16383; int h = r >> 7; int d = r & 127;
        WmT[i] = (bf16)Wmsg[e*Dd*Dd + d*Dd + h];
    }
    for (int i = tid; i < 384*Dd; i += stride){
        int j = i >> 7; int d = i & 127;
        WiT[i] = (bf16)Wi[d*384 + j];
        WhT[i] = (bf16)Wh[d*384 + j];
    }
    for (int i = tid; i < Dd*Dd; i += stride){
        int h = i >> 7; int d = i & 127;
        ArT[i] = (bf16)Ar[d*Dd + h];
    }
}

// ---------------------------------------------------------------------------
// Per-edge transform: Pt[s][h][e] = (hb @ W_e)[s][h]  (k-major layout)
// grid (32 s-tiles of 64, 8 h-tiles of 16), block 256 (4 waves x 16 s rows)
// ---------------------------------------------------------------------------
__global__ __launch_bounds__(256) void k_per_edge(
    const bf16* __restrict__ hb, const bf16* __restrict__ WmT,
    bf16* __restrict__ Pt)
{
    __shared__ bf16 Blds[Ee][16][Dd+8];             // 34,816 B
    const int s0 = blockIdx.x * 64;
    const int h0 = blockIdx.y * 16;
    const int tid = threadIdx.x;
    for (int i = 0; i < 8; i++){
        int idx = tid + i*256;                      // 2048 chunks of 8
        int e = idx >> 8, row = (idx >> 4) & 15, c = idx & 15;
        *(bf16x8*)&Blds[e][row][c*8] =
            *(const bf16x8*)&WmT[e*Dd*Dd + (h0+row)*Dd + c*8];
    }
    __syncthreads();
    const int lane = tid & 63, wave = tid >> 6;
    const int quad = lane >> 4, l16 = lane & 15;
    const int srow = s0 + wave*16 + l16;
    f32x4 acc[Ee];
    for (int e = 0; e < Ee; e++) acc[e] = (f32x4){0.f,0.f,0.f,0.f};
    for (int kk = 0; kk < 4; kk++){
        int k0 = kk*32 + quad*8;
        bf16x8 a = *(const bf16x8*)&hb[srow*Dd + k0];
        for (int e = 0; e < Ee; e++){
            bf16x8 b = *(const bf16x8*)&Blds[e][l16][k0];
            acc[e] = mfma16(a, b, acc[e]);
        }
    }
    const int h = h0 + l16;
    for (int r = 0; r < 4; r++){
        int s = s0 + wave*16 + quad*4 + r;
        bf16x8 po;
        for (int e = 0; e < Ee; e++) po[e] = (bf16)acc[e][r];
        *(bf16x8*)&Pt[((size_t)s*Dd + h)*Ee] = po;   // k-major [s][h][e]
    }
}

// ---------------------------------------------------------------------------
// msgP[kg][t][h] = sum_{k in group} edge[t][k] * Pt-as-B[h][k],  k = s*8+e
// R6 proven version: KSPLIT=32, 512 blocks (2/CU), 2-buffer 64KB pipeline,
// one-chunk lookahead. FIRST=1: fp32 edge read + in-register convert +
// persist bf16. XCD swizzle: kgroup = (flat&7)*4 + ((flat>>3)&3).
// ---------------------------------------------------------------------------
template<int FIRST>
__global__ __launch_bounds__(256) void k_msg_gemm(
    const float* __restrict__ edge_f, bf16* __restrict__ edge_bf,
    const bf16* __restrict__ Pt, bf16* __restrict__ msgP)
{
    __shared__ __align__(16) char ldsb[65536];      // 2 x 32KB Pt tiles
    const int flat = blockIdx.y*32 + blockIdx.x;    // grid (32,16) -> 512
    const int kgroup = (flat & 7)*4 + ((flat >> 3) & 3);
    const int tgroup = flat >> 5;
    const int t0 = tgroup * 128;
    const int sblk = kgroup * 64;                   // 64 s = 512 k per block
    const int tid = threadIdx.x;
    const int lane = tid & 63, wave = tid >> 6;
    const int half = lane >> 5, l31 = lane & 31;
    const int trow = t0 + wave*32 + l31;
    const char* Ptb = (const char*)Pt;

    f32x16 acc[4];
    #pragma unroll
    for (int nt = 0; nt < 4; nt++)
        for (int i = 0; i < 16; i++) acc[nt][i] = 0.f;

    bf16x8 A0[8], A1[8];

#define STAGE(ch_) do{                                                         \
    const char* _src = Ptb + (size_t)(sblk + (ch_)*16)*2048                    \
                           + wave*1024 + lane*16;                              \
    char* _dst = ldsb + ((ch_)&1)*32768 + wave*1024;                           \
    _Pragma("unroll")                                                          \
    for (int j = 0; j < 8; j++)                                                \
        g2lds16(_src + j*4096, _dst + j*4096);                                 \
}while(0)

#define PREF(AD_, ch_) do{                                                     \
    int _sc = sblk + (ch_)*16 + half;                                          \
    _Pragma("unroll")                                                          \
    for (int ks = 0; ks < 8; ks++){                                            \
        size_t _off = (size_t)(_sc + ks*2)*16384 + trow*8;                     \
        if (FIRST){                                                            \
            f32x4 _v0 = *(const f32x4*)&edge_f[_off];                          \
            f32x4 _v1 = *(const f32x4*)&edge_f[_off+4];                        \
            bf16x8 _o;                                                         \
            for (int _j = 0; _j < 4; _j++){                                    \
                _o[_j] = (bf16)_v0[_j]; _o[_j+4] = (bf16)_v1[_j];              \
            }                                                                  \
            AD_[ks] = _o;                                                      \
            *(bf16x8*)&edge_bf[_off] = _o;                                     \
        } else {                                                               \
            AD_[ks] = *(const bf16x8*)&edge_bf[_off];                          \
        }                                                                      \
    }                                                                          \
}while(0)

#define COMPUTE(AD_, ch_) do{                                                  \
    const bf16* _bt = (const bf16*)(ldsb + ((ch_)&1)*32768);                   \
    _Pragma("unroll")                                                          \
    for (int ks = 0; ks < 8; ks++){                                            \
        const bf16* _bp = _bt + (ks*2 + half)*1024 + l31*8;                    \
        acc[0] = mfma32(AD_[ks], *(const bf16x8*)(_bp      ), acc[0]);         \
        acc[1] = mfma32(AD_[ks], *(const bf16x8*)(_bp + 256), acc[1]);         \
        acc[2] = mfma32(AD_[ks], *(const bf16x8*)(_bp + 512), acc[2]);         \
        acc[3] = mfma32(AD_[ks], *(const bf16x8*)(_bp + 768), acc[3]);         \
    }                                                                          \
}while(0)

    STAGE(0); PREF(A0, 0);
    asm volatile("s_waitcnt vmcnt(0)" ::: "memory");
    __syncthreads();
    #pragma unroll
    for (int cc = 0; cc < 2; cc++){
        const int ch = cc*2;
        STAGE(ch+1); PREF(A1, ch+1);
        COMPUTE(A0, ch);
        asm volatile("s_waitcnt vmcnt(0)" ::: "memory");
        __syncthreads();
        if (ch+2 < 4){ STAGE(ch+2); PREF(A0, ch+2); }
        COMPUTE(A1, ch+1);
        if (ch+2 < 4){
            asm volatile("s_waitcnt vmcnt(0)" ::: "memory");
            __syncthreads();
        }
    }
#undef STAGE
#undef PREF
#undef COMPUTE

    // C/D layout 32x32: col = lane&31, row = (r&3) + 8*(r>>2) + 4*(lane>>5)
    bf16* dst = msgP + (size_t)kgroup*(Nn*Dd);
    #pragma unroll
    for (int nt = 0; nt < 4; nt++){
        int h = nt*32 + l31;
        #pragma unroll
        for (int r = 0; r < 16; r++){
            int row = (r&3) + 8*(r>>2) + 4*half;
            dst[(size_t)(t0 + wave*32 + row)*Dd + h] = (bf16)acc[nt][r];
        }
    }
}

// ---------------------------------------------------------------------------
// GRU v3 — full-chip, barrier-minimal:
//   grid 256 x 8 t-rows (1 block/CU), TWO __syncthreads total (was 17).
//   Phase A: reduce 32 bf16 partials + b_msg in fp32 p-order (bit-identical
//     per element to R9), stage msg + h to zero-padded LDS rows [0..7].
//   Phase B: Gi and Gh GEMMs with B-fragments read DIRECTLY from global
//     (L2-hot 192 KB; R3-proven pattern) -- no weight staging, no barriers;
//     48 independent loads/thread pipeline behind 48 mfma16.
//     MFMA rows 8..15 run on zeros and are discarded.
//   Phase C: gates; Gi+Gh summed in fp32 here (reassociated vs R9's shared
//     accumulator -- absmax drift ~1e-6, invisible at 2.9e-3 scale).
// ---------------------------------------------------------------------------
__global__ __launch_bounds__(256) void k_gru3(
    const bf16* __restrict__ msgP, const float* __restrict__ bmsg,
    const bf16* __restrict__ WiT, const bf16* __restrict__ WhT,
    const float* __restrict__ bgru,
    float* __restrict__ h32, bf16* __restrict__ hb)
{
    __shared__ __align__(16) bf16 msg_b[16][136];   // rows 8..15 zero
    __shared__ __align__(16) bf16 h_b[16][136];     // rows 8..15 zero
    __shared__ float Gs [8][388];                    // Gi (full 384)
    __shared__ float Ghf[8][388];                    // Gh (full 384)

    const int t0 = blockIdx.x * 8;
    const int tid = threadIdx.x;
    const int lane = tid & 63, wave = tid >> 6;
    const int quad = lane >> 4, l16 = lane & 15;

    // zero pad rows 8..15 (A-frag reads l16 up to 15)
    for (int i = tid; i < 8*136; i += 256){
        (&msg_b[8][0])[i] = (bf16)0.f;
        (&h_b [8][0])[i] = (bf16)0.f;
    }

    // ---- Phase A: reduce KSPLIT partials + b_msg; stage msg + h ----
    {
        int m = tid >> 5;                 // 0..7
        int d0 = (tid & 31) * 4;          // 0..124
        f32x4 s = *(const f32x4*)&bmsg[d0];
        #pragma unroll
        for (int p = 0; p < KSPLIT; p++){
            bf16x4 v = *(const bf16x4*)&msgP[(size_t)p*Nn*Dd + (t0+m)*Dd + d0];
            #pragma unroll
            for (int j = 0; j < 4; j++) s[j] += (float)v[j];
        }
        bf16x4 o;
        #pragma unroll
        for (int j = 0; j < 4; j++) o[j] = (bf16)s[j];
        *(bf16x4*)&msg_b[m][d0] = o;
        *(bf16x4*)&h_b[m][d0] = *(const bf16x4*)&hb[(t0+m)*Dd + d0];
    }
    __syncthreads();

    // ---- Phase B: 48 j-tiles (24 Gi + 24 Gh), 12 per wave, no barriers ----
    f32x4 accA[12];
    #pragma unroll
    for (int i = 0; i < 12; i++) accA[i] = (f32x4){0.f,0.f,0.f,0.f};
    #pragma unroll
    for (int kc = 0; kc < 4; kc++){
        int k0 = kc*32 + quad*8;
        bf16x8 aGi = *(const bf16x8*)&msg_b[l16][k0];
        bf16x8 aGh = *(const bf16x8*)&h_b[l16][k0];
        #pragma unroll
        for (int i = 0; i < 12; i++){
            int T = wave*12 + i;
            int isGi = T < 24;
            int jt = isGi ? T : T - 24;
            const bf16* WT = isGi ? WiT : WhT;
            bf16x8 b = *(const bf16x8*)&WT[(jt*16 + l16)*Dd + k0];
            accA[i] = mfma16(isGi ? aGi : aGh, b, accA[i]);
        }
    }
    #pragma unroll
    for (int i = 0; i < 12; i++){
        int T = wave*12 + i;
        int jt = T < 24 ? T : T - 24;
        float* G = T < 24 ? &Gs[0][0] : &Ghf[0][0];
        #pragma unroll
        for (int r = 0; r < 4; r++){
            int row = quad*4 + r;
            if (row < 8) G[row*388 + jt*16 + l16] = accA[i][r];
        }
    }
    __syncthreads();

    // ---- Phase C: gates + h update (8 rows x 128, 4 cells/thread) ----
    #pragma unroll
    for (int i = 0; i < 4; i++){
        int cell = tid + i*256;
        int m = cell >> 7, jd = cell & 127;
        int t = t0 + m;
        float xr = Gs[m][jd]       + Ghf[m][jd]       + bgru[jd];
        float xz = Gs[m][128 + jd] + Ghf[m][128 + jd] + bgru[128 + jd];
        float xn = Gs[m][256 + jd] + bgru[256 + jd];
        float r = 1.f / (1.f + expf(-xr));
        float z = 1.f / (1.f + expf(-xz));
        float n = tanhf(xn + r * Ghf[m][256 + jd]);
        float ho = h32[t*Dd + jd];
        float hnew = (1.f - z) * n + z * ho;
        h32[t*Dd + jd] = hnew;
        hb [t*Dd + jd] = (bf16)hnew;
    }
}

// ---------------------------------------------------------------------------
// Readout 1: t1 = hb @ A_readout  (via ArT[h][d]), bf16 out (internal)
// ---------------------------------------------------------------------------
__global__ __launch_bounds__(256) void k_read1(
    const bf16* __restrict__ hb, const bf16* __restrict__ ArT, bf16* __restrict__ t1)
{
    __shared__ bf16 Blds[Dd][Dd+8];
    const int s0 = blockIdx.x * 64;
    const int tid = threadIdx.x;
    for (int i = 0; i < 8; i++){
        int idx = tid + i*256; int row = idx >> 4, c = idx & 15;
        *(bf16x8*)&Blds[row][c*8] = *(const bf16x8*)&ArT[row*Dd + c*8];
    }
    __syncthreads();
    const int lane = tid & 63, wave = tid >> 6;
    const int quad = lane >> 4, l16 = lane & 15;
    const int srow = s0 + wave*16 + l16;
    f32x4 acc[8];
    for (int nt = 0; nt < 8; nt++) acc[nt] = (f32x4){0.f,0.f,0.f,0.f};
    for (int kk = 0; kk < 4; kk++){
        int k0 = kk*32 + quad*8;
        bf16x8 a = *(const bf16x8*)&hb[srow*Dd + k0];
        for (int nt = 0; nt < 8; nt++){
            bf16x8 b = *(const bf16x8*)&Blds[nt*16 + l16][k0];
            acc[nt] = mfma16(a, b, acc[nt]);
        }
    }
    for (int nt = 0; nt < 8; nt++){
        int h = nt*16 + l16;
        for (int r = 0; r < 4; r++){
            int s = s0 + wave*16 + quad*4 + r;
            t1[s*Dd + h] = (bf16)acc[nt][r];
        }
    }
}

// ---------------------------------------------------------------------------
// Readout 2: logits[i][j] = sum_d t1[i][d]*hb[j][d], fp32 out
// ---------------------------------------------------------------------------
__global__ __launch_bounds__(256) void k_read2(
    const bf16* __restrict__ t1, const bf16* __restrict__ hb, float* __restrict__ out)
{
    const int i0 = blockIdx.x * 64, j0 = blockIdx.y * 128;
    const int tid = threadIdx.x;
    const int lane = tid & 63, wave = tid >> 6;
    const int quad = lane >> 4, l16 = lane & 15;
    const int irow = i0 + wave*16 + l16;
    f32x4 acc[8];
    for (int nt = 0; nt < 8; nt++) acc[nt] = (f32x4){0.f,0.f,0.f,0.f};
    for (int kk = 0; kk < 4; kk++){
        int k0 = kk*32 + quad*8;
        bf16x8 a = *(const bf16x8*)&t1[irow*Dd + k0];
        for (int nt = 0; nt < 8; nt++){
            int j = j0 + nt*16 + l16;
            bf16x8 b = *(const bf16x8*)&hb[j*Dd + k0];
            acc[nt] = mfma16(a, b, acc[nt]);
        }
    }
    for (int nt = 0; nt < 8; nt++){
        int j = j0 + nt*16 + l16;
        for (int r = 0; r < 4; r++){
            int irw = i0 + wave*16 + quad*4 + r;
            out[(size_t)irw*Nn + j] = acc[nt][r];
        }
    }
}

// ---------------------------------------------------------------------------
extern "C" void kernel_launch(void* const* d_in, const int* in_sizes, int n_in,
                              void* d_out, int out_size, void* d_ws, size_t ws_size,
                              hipStream_t stream)
{
    const float* node = (const float*)d_in[0];
    const float* edge = (const float*)d_in[1];
    const float* Wmsg = (const float*)d_in[2];
    const float* bmsg = (const float*)d_in[3];
    const float* Wi   = (const float*)d_in[4];
    const float* Wh   = (const float*)d_in[5];
    const float* bgru = (const float*)d_in[6];
    const float* Ar   = (const float*)d_in[7];
    float* out = (float*)d_out;

    char* ws = (char*)d_ws;
    bf16*  edge_bf = (bf16*)ws;          ws += (size_t)Nn*Nn*Ee*2;      // 64 MiB
    bf16*  msgP = (bf16*)ws;             ws += (size_t)KSPLIT*Nn*Dd*2;  // 16 MiB
    bf16*  Pt  = (bf16*)ws;              ws += (size_t)Dd*KT*2;         //  4 MiB
    float* h32 = (float*)ws;             ws += (size_t)Nn*Dd*4;
    bf16*  hb  = (bf16*)ws;              ws += (size_t)Nn*Dd*2;
    bf16*  WmT = (bf16*)ws;              ws += (size_t)Ee*Dd*Dd*2;
    bf16*  WiT = (bf16*)ws;              ws += (size_t)384*Dd*2;
    bf16*  WhT = (bf16*)ws;              ws += (size_t)384*Dd*2;
    bf16*  ArT = (bf16*)ws;              ws += (size_t)Dd*Dd*2;
    bf16*  t1  = (bf16*)ws;              ws += (size_t)Nn*Dd*2;

    k_prep<<<dim3(256), 256, 0, stream>>>(node, Wmsg, Wi, Wh, Ar,
                                          h32, hb, WmT, WiT, WhT, ArT);
    for (int it = 0; it < NIT; it++){
        k_per_edge<<<dim3(32, 8), 256, 0, stream>>>(hb, WmT, Pt);
        if (it == 0)
            k_msg_gemm<1><<<dim3(32,16), 256, 0, stream>>>(edge, edge_bf, Pt, msgP);
        else
            k_msg_gemm<0><<<dim3(32,16), 256, 0, stream>>>(edge, edge_bf, Pt, msgP);
        k_gru3<<<dim3(256), 256, 0, stream>>>(msgP, bmsg, WiT, WhT, bgru, h32, hb);
    }
    k_read1<<<dim3(32),     256, 0, stream>>>(hb, ArT, t1);
    k_read2<<<dim3(32, 16), 256, 0, stream>>>(t1, hb, out);
}